// Round 1
// baseline (259.122 us; speedup 1.0000x reference)
//
#include <hip/hip_runtime.h>
#include <hip/hip_bf16.h>

#define NROWS 400000
#define MSEL  100000
#define FDIM  128
#define D0 256
#define D1 256
#define D2 128

typedef __attribute__((ext_vector_type(8))) short short8;
typedef __attribute__((ext_vector_type(4))) float f32x4;
typedef __attribute__((ext_vector_type(4))) unsigned short ushort4v;

__device__ __forceinline__ unsigned short f2bf(float f) {
    unsigned int u = __float_as_uint(f);
    unsigned int r = (u + 0x7fffu + ((u >> 16) & 1u)) >> 16;
    return (unsigned short)r;
}

__device__ __forceinline__ float elu(float v) {
    return v > 0.f ? v : (__expf(v) - 1.f);
}

// ---------------------------------------------------------------------------
// Repack f32 weights into bf16 "B-fragment order" for mfma_f32_16x16x32_bf16.
// Tile (kt,nt) is 32x16; within a tile, lane l holds B[kt*32+(l>>4)*8+j][nt*16+(l&15)]
// stored contiguously (8 bf16 = 16B per lane) so a B-frag load is one dwordx4.
// Layout in ws: W0p [0,32768) shorts, W1p [32768,98304), W2p [98304,131072).
// ---------------------------------------------------------------------------
__global__ void pack_weights(const float* __restrict__ W0,
                             const float* __restrict__ W1,
                             const float* __restrict__ W2,
                             short* __restrict__ out) {
    int e = blockIdx.x * 256 + threadIdx.x;
    if (e >= 131072) return;
    const float* W; int N; int base; int le;
    if (e < 32768)       { W = W0; N = 256; base = 0;     le = e; }
    else if (e < 98304)  { W = W1; N = 256; base = 32768; le = e - 32768; }
    else                 { W = W2; N = 128; base = 98304; le = e - 98304; }
    int t    = le >> 9;          // tile index
    int r    = le & 511;
    int lane = r >> 3;
    int j    = r & 7;
    int ntiles = N >> 4;
    int kt = t / ntiles, nt = t % ntiles;
    int k = kt * 32 + (lane >> 4) * 8 + j;
    int n = nt * 16 + (lane & 15);
    out[base + le] = (short)f2bf(W[k * N + n]);
}

// ---------------------------------------------------------------------------
// out = x  (full copy, vectorized)
// ---------------------------------------------------------------------------
__global__ void copy_x(const float4* __restrict__ x, float4* __restrict__ out, int n4) {
    int i = blockIdx.x * blockDim.x + threadIdx.x;
    int stride = gridDim.x * blockDim.x;
    for (; i < n4; i += stride) out[i] = x[i];
}

// ---------------------------------------------------------------------------
// Fused gather -> 3-layer ELU MLP (bf16 MFMA) -> atomic scatter-add.
// Block = 256 threads = 4 waves; each wave owns 16 of the block's 64 rows.
// LDS (64KB shorts):
//   region A  [0,16384)      : h0 (64 x 256 bf16)
//   region B  [16384,32768)  : gathered x (64 x 128 bf16), later h1 (64 x 256)
// All LDS addressing XOR-swizzled: shortIdx ^= (row&7)<<3  (byte ^ (row&7)<<4)
// to break the same-bank stride on ds_read_b128 A-fragments.
// ---------------------------------------------------------------------------
__global__ __launch_bounds__(256) void mlp_kernel(
    const float* __restrict__ x, const int* __restrict__ sel,
    const short* __restrict__ wp,
    const float* __restrict__ b0v, const float* __restrict__ b1v,
    const float* __restrict__ b2v, float* __restrict__ out) {
    __shared__ __align__(16) short lds[32768];

    const int tid  = threadIdx.x;
    const int lane = tid & 63;
    const int w    = tid >> 6;
    const int rowBase = blockIdx.x * 64;
    const int lm = lane & 15;   // col within 16x16 tile (also A-frag row offset)
    const int kq = lane >> 4;   // k-quad 0..3

    const short* W0p = wp;
    const short* W1p = wp + 32768;
    const short* W2p = wp + 98304;

    // ---- gather: 64 rows x 128 f32 -> bf16 into region B ----
    const float4* xv = (const float4*)x;
    for (int i = tid; i < 64 * 32; i += 256) {
        int row = i >> 5, seg = i & 31;
        int grow = rowBase + row;
        float4 v;
        if (grow < MSEL) {
            v = xv[(size_t)sel[grow] * 32 + seg];
        } else {
            v.x = v.y = v.z = v.w = 0.f;
        }
        ushort4v p = { f2bf(v.x), f2bf(v.y), f2bf(v.z), f2bf(v.w) };
        int si = (16384 + row * 128 + seg * 4) ^ ((row & 7) << 3);
        *(ushort4v*)(&lds[si]) = p;
    }
    __syncthreads();

    const int wr   = w * 16;         // wave's row offset within the 64-row tile
    const int rowA = wr + lm;        // this lane's A-fragment row
    const int sxz  = (rowA & 7) << 3;
    const f32x4 zero4 = {0.f, 0.f, 0.f, 0.f};

    // ================= layer 0: (64x128) @ W0(128x256) =================
    f32x4 acc[16];
    #pragma unroll
    for (int i = 0; i < 16; i++) acc[i] = zero4;
    short8 a0[4];
    #pragma unroll
    for (int kt = 0; kt < 4; kt++)
        a0[kt] = *(const short8*)(&lds[(16384 + rowA * 128 + kt * 32 + kq * 8) ^ sxz]);
    #pragma unroll
    for (int nt = 0; nt < 16; nt++) {
        #pragma unroll
        for (int kt = 0; kt < 4; kt++) {
            short8 b = *(const short8*)(W0p + ((kt * 16 + nt) * 512 + lane * 8));
            acc[nt] = __builtin_amdgcn_mfma_f32_16x16x32_bf16(a0[kt], b, acc[nt], 0, 0, 0);
        }
    }
    // epilogue 0: bias+ELU -> h0 (region A, stride 256)
    #pragma unroll
    for (int nt = 0; nt < 16; nt++) {
        int col = nt * 16 + lm;
        float bias = b0v[col];
        #pragma unroll
        for (int r = 0; r < 4; r++) {
            int row = wr + kq * 4 + r;
            float v = elu(acc[nt][r] + bias);
            lds[(row * 256 + col) ^ ((row & 7) << 3)] = (short)f2bf(v);
        }
    }
    __syncthreads();

    // ================= layer 1: (64x256) @ W1(256x256) =================
    #pragma unroll
    for (int i = 0; i < 16; i++) acc[i] = zero4;
    short8 a1[8];
    #pragma unroll
    for (int kt = 0; kt < 8; kt++)
        a1[kt] = *(const short8*)(&lds[(rowA * 256 + kt * 32 + kq * 8) ^ sxz]);
    #pragma unroll
    for (int nt = 0; nt < 16; nt++) {
        #pragma unroll
        for (int kt = 0; kt < 8; kt++) {
            short8 b = *(const short8*)(W1p + ((kt * 16 + nt) * 512 + lane * 8));
            acc[nt] = __builtin_amdgcn_mfma_f32_16x16x32_bf16(a1[kt], b, acc[nt], 0, 0, 0);
        }
    }
    // epilogue 1: bias+ELU -> h1 (region B, stride 256)
    #pragma unroll
    for (int nt = 0; nt < 16; nt++) {
        int col = nt * 16 + lm;
        float bias = b1v[col];
        #pragma unroll
        for (int r = 0; r < 4; r++) {
            int row = wr + kq * 4 + r;
            float v = elu(acc[nt][r] + bias);
            lds[(16384 + row * 256 + col) ^ ((row & 7) << 3)] = (short)f2bf(v);
        }
    }
    __syncthreads();

    // ================= layer 2: (64x256) @ W2(256x128) =================
    f32x4 acc2[8];
    #pragma unroll
    for (int i = 0; i < 8; i++) acc2[i] = zero4;
    short8 a2[8];
    #pragma unroll
    for (int kt = 0; kt < 8; kt++)
        a2[kt] = *(const short8*)(&lds[(16384 + rowA * 256 + kt * 32 + kq * 8) ^ sxz]);
    #pragma unroll
    for (int nt = 0; nt < 8; nt++) {
        #pragma unroll
        for (int kt = 0; kt < 8; kt++) {
            short8 b = *(const short8*)(W2p + ((kt * 8 + nt) * 512 + lane * 8));
            acc2[nt] = __builtin_amdgcn_mfma_f32_16x16x32_bf16(a2[kt], b, acc2[nt], 0, 0, 0);
        }
    }
    // epilogue 2: bias+ELU -> atomic scatter-add into out
    int gi[4];
    #pragma unroll
    for (int r = 0; r < 4; r++) {
        int grow = rowBase + wr + kq * 4 + r;
        gi[r] = (grow < MSEL) ? sel[grow] : -1;
    }
    #pragma unroll
    for (int nt = 0; nt < 8; nt++) {
        int col = nt * 16 + lm;
        float bias = b2v[col];
        #pragma unroll
        for (int r = 0; r < 4; r++) {
            if (gi[r] >= 0) {
                float v = elu(acc2[nt][r] + bias);
                atomicAdd(out + (size_t)gi[r] * 128 + col, v);
            }
        }
    }
}

extern "C" void kernel_launch(void* const* d_in, const int* in_sizes, int n_in,
                              void* d_out, int out_size, void* d_ws, size_t ws_size,
                              hipStream_t stream) {
    const float* x   = (const float*)d_in[0];
    const int*   sel = (const int*)d_in[1];
    const float* W0  = (const float*)d_in[2];
    const float* b0  = (const float*)d_in[3];
    const float* W1  = (const float*)d_in[4];
    const float* b1  = (const float*)d_in[5];
    const float* W2  = (const float*)d_in[6];
    const float* b2  = (const float*)d_in[7];
    float* out = (float*)d_out;
    short* wp  = (short*)d_ws;   // needs 262144 bytes

    pack_weights<<<512, 256, 0, stream>>>(W0, W1, W2, wp);
    copy_x<<<4096, 256, 0, stream>>>((const float4*)x, (float4*)out, NROWS * FDIM / 4);
    mlp_kernel<<<(MSEL + 63) / 64, 256, 0, stream>>>(x, sel, wp, b0, b1, b2, out);
}

// Round 2
// 207.717 us; speedup vs baseline: 1.2475x; 1.2475x over previous
//
#include <hip/hip_runtime.h>
#include <hip/hip_bf16.h>

#define NROWS 400000
#define MSEL  100000
#define FDIM  128
#define D0 256
#define D1 256
#define D2 128

typedef __attribute__((ext_vector_type(8))) short short8;
typedef __attribute__((ext_vector_type(4))) float f32x4;
typedef __attribute__((ext_vector_type(4))) unsigned short ushort4v;

__device__ __forceinline__ unsigned short f2bf(float f) {
    unsigned int u = __float_as_uint(f);
    unsigned int r = (u + 0x7fffu + ((u >> 16) & 1u)) >> 16;
    return (unsigned short)r;
}

__device__ __forceinline__ float elu(float v) {
    return v > 0.f ? v : (__expf(v) - 1.f);
}

// ---------------------------------------------------------------------------
// Repack f32 weights into bf16 "B-fragment order" for mfma_f32_16x16x32_bf16.
// Tile (kt,nt) is 32x16; within a tile, lane l holds B[kt*32+(l>>4)*8+j][nt*16+(l&15)]
// stored contiguously (8 bf16 = 16B per lane) so a B-frag load is one dwordx4.
// Layout in ws: W0p [0,32768) shorts, W1p [32768,98304), W2p [98304,131072).
// ---------------------------------------------------------------------------
__global__ void pack_weights(const float* __restrict__ W0,
                             const float* __restrict__ W1,
                             const float* __restrict__ W2,
                             short* __restrict__ out) {
    int e = blockIdx.x * 256 + threadIdx.x;
    if (e >= 131072) return;
    const float* W; int N; int base; int le;
    if (e < 32768)       { W = W0; N = 256; base = 0;     le = e; }
    else if (e < 98304)  { W = W1; N = 256; base = 32768; le = e - 32768; }
    else                 { W = W2; N = 128; base = 98304; le = e - 98304; }
    int t    = le >> 9;          // tile index
    int r    = le & 511;
    int lane = r >> 3;
    int j    = r & 7;
    int ntiles = N >> 4;
    int kt = t / ntiles, nt = t % ntiles;
    int k = kt * 32 + (lane >> 4) * 8 + j;
    int n = nt * 16 + (lane & 15);
    out[base + le] = (short)f2bf(W[k * N + n]);
}

// ---------------------------------------------------------------------------
// out = x  (full copy, vectorized)
// ---------------------------------------------------------------------------
__global__ void copy_x(const float4* __restrict__ x, float4* __restrict__ out, int n4) {
    int i = blockIdx.x * blockDim.x + threadIdx.x;
    int stride = gridDim.x * blockDim.x;
    for (; i < n4; i += stride) out[i] = x[i];
}

// ---------------------------------------------------------------------------
// Fused gather -> 3-layer ELU MLP (bf16 MFMA) -> atomic scatter-add.
// Block = 256 threads = 4 waves, 64 rows/block.
// Wave decomposition: each wave computes ALL 64 rows x a 64-col slice
// (32-col slice for layer 2), so its B-fragments are register-resident per
// layer (16/32/16 frags) and reused across 4 row-tiles. Steady state is
// ds_read_b128 + MFMA; global loads are batched at layer start.
// LDS (64KB shorts):
//   region A  [0,16384)      : h0 (64 x 256 bf16)
//   region B  [16384,32768)  : gathered x (64 x 128 bf16), later h1 (64 x 256)
// XOR swizzle: shortIdx ^= (row&7)<<3 to break ds_read_b128 bank conflicts.
// ---------------------------------------------------------------------------
__global__ __launch_bounds__(256) void mlp_kernel(
    const float* __restrict__ x, const int* __restrict__ sel,
    const short* __restrict__ wp,
    const float* __restrict__ b0v, const float* __restrict__ b1v,
    const float* __restrict__ b2v, float* __restrict__ out) {
    __shared__ __align__(16) short lds[32768];

    const int tid  = threadIdx.x;
    const int lane = tid & 63;
    const int w    = tid >> 6;
    const int rowBase = blockIdx.x * 64;
    const int lm = lane & 15;   // col within 16x16 tile / A-frag row offset
    const int kq = lane >> 4;   // k-quad 0..3
    const int sxz = (lm & 7) << 3;   // A-frag swizzle (row&7 == lm&7 since rt*16 is 8-aligned)

    const short* W0p = wp;
    const short* W1p = wp + 32768;
    const short* W2p = wp + 98304;

    // ---- prefetch layer-0 B fragments (hide under gather) ----
    short8 B0[4][4];   // [kt][ntl], wave's cols = (w*4+ntl)*16 .. +15
    #pragma unroll
    for (int kt = 0; kt < 4; kt++)
        #pragma unroll
        for (int ntl = 0; ntl < 4; ntl++)
            B0[kt][ntl] = *(const short8*)(W0p + ((kt * 16 + (w * 4 + ntl)) * 512 + lane * 8));

    // ---- gather: 64 rows x 128 f32 -> bf16 into region B ----
    const float4* xv = (const float4*)x;
    for (int i = tid; i < 64 * 32; i += 256) {
        int row = i >> 5, seg = i & 31;
        int grow = rowBase + row;
        float4 v;
        if (grow < MSEL) {
            v = xv[(size_t)sel[grow] * 32 + seg];
        } else {
            v.x = v.y = v.z = v.w = 0.f;
        }
        ushort4v p = { f2bf(v.x), f2bf(v.y), f2bf(v.z), f2bf(v.w) };
        int si = (16384 + row * 128 + seg * 4) ^ ((row & 7) << 3);
        *(ushort4v*)(&lds[si]) = p;
    }
    __syncthreads();

    const f32x4 zero4 = {0.f, 0.f, 0.f, 0.f};

    // ================= layer 0: (64x128) @ W0(128x256) =================
    {
        f32x4 acc[4][4];   // [rt][ntl]
        #pragma unroll
        for (int i = 0; i < 4; i++)
            #pragma unroll
            for (int j = 0; j < 4; j++) acc[i][j] = zero4;
        #pragma unroll
        for (int rt = 0; rt < 4; rt++) {
            short8 a[4];
            int rowA = rt * 16 + lm;
            #pragma unroll
            for (int kt = 0; kt < 4; kt++)
                a[kt] = *(const short8*)(&lds[(16384 + rowA * 128 + kt * 32 + kq * 8) ^ sxz]);
            #pragma unroll
            for (int ntl = 0; ntl < 4; ntl++)
                #pragma unroll
                for (int kt = 0; kt < 4; kt++)
                    acc[rt][ntl] = __builtin_amdgcn_mfma_f32_16x16x32_bf16(a[kt], B0[kt][ntl], acc[rt][ntl], 0, 0, 0);
        }
        // epilogue: bias+ELU -> h0 (region A)
        #pragma unroll
        for (int ntl = 0; ntl < 4; ntl++) {
            int col = (w * 4 + ntl) * 16 + lm;
            float bias = b0v[col];
            #pragma unroll
            for (int rt = 0; rt < 4; rt++)
                #pragma unroll
                for (int r = 0; r < 4; r++) {
                    int row = rt * 16 + kq * 4 + r;
                    float v = elu(acc[rt][ntl][r] + bias);
                    lds[(row * 256 + col) ^ ((row & 7) << 3)] = (short)f2bf(v);
                }
        }
    }
    __syncthreads();

    // ================= layer 1: (64x256) @ W1(256x256), 2 col-passes =================
    #pragma unroll
    for (int pass = 0; pass < 2; pass++) {
        short8 B1[8][2];
        #pragma unroll
        for (int kt = 0; kt < 8; kt++)
            #pragma unroll
            for (int p = 0; p < 2; p++) {
                int ntl = pass * 2 + p;
                B1[kt][p] = *(const short8*)(W1p + ((kt * 16 + (w * 4 + ntl)) * 512 + lane * 8));
            }
        f32x4 acc[4][2];
        #pragma unroll
        for (int i = 0; i < 4; i++)
            #pragma unroll
            for (int j = 0; j < 2; j++) acc[i][j] = zero4;
        #pragma unroll
        for (int rt = 0; rt < 4; rt++) {
            short8 a[8];
            int rowA = rt * 16 + lm;
            #pragma unroll
            for (int kt = 0; kt < 8; kt++)
                a[kt] = *(const short8*)(&lds[(rowA * 256 + kt * 32 + kq * 8) ^ sxz]);
            #pragma unroll
            for (int p = 0; p < 2; p++)
                #pragma unroll
                for (int kt = 0; kt < 8; kt++)
                    acc[rt][p] = __builtin_amdgcn_mfma_f32_16x16x32_bf16(a[kt], B1[kt][p], acc[rt][p], 0, 0, 0);
        }
        // epilogue: bias+ELU -> h1 (region B; x is dead after layer 0 + barrier)
        #pragma unroll
        for (int p = 0; p < 2; p++) {
            int col = (w * 4 + pass * 2 + p) * 16 + lm;
            float bias = b1v[col];
            #pragma unroll
            for (int rt = 0; rt < 4; rt++)
                #pragma unroll
                for (int r = 0; r < 4; r++) {
                    int row = rt * 16 + kq * 4 + r;
                    float v = elu(acc[rt][p][r] + bias);
                    lds[(16384 + row * 256 + col) ^ ((row & 7) << 3)] = (short)f2bf(v);
                }
        }
    }
    __syncthreads();

    // ================= layer 2: (64x256) @ W2(256x128) =================
    {
        short8 B2[8][2];   // wave's cols = (w*2+ntl)*16 .. +15  (ntiles=8)
        #pragma unroll
        for (int kt = 0; kt < 8; kt++)
            #pragma unroll
            for (int ntl = 0; ntl < 2; ntl++)
                B2[kt][ntl] = *(const short8*)(W2p + ((kt * 8 + (w * 2 + ntl)) * 512 + lane * 8));

        int gi[4][4];
        #pragma unroll
        for (int rt = 0; rt < 4; rt++)
            #pragma unroll
            for (int r = 0; r < 4; r++) {
                int grow = rowBase + rt * 16 + kq * 4 + r;
                gi[rt][r] = (grow < MSEL) ? sel[grow] : -1;
            }

        f32x4 acc[4][2];
        #pragma unroll
        for (int i = 0; i < 4; i++)
            #pragma unroll
            for (int j = 0; j < 2; j++) acc[i][j] = zero4;
        #pragma unroll
        for (int rt = 0; rt < 4; rt++) {
            short8 a[8];
            int rowA = rt * 16 + lm;
            #pragma unroll
            for (int kt = 0; kt < 8; kt++)
                a[kt] = *(const short8*)(&lds[(16384 + rowA * 256 + kt * 32 + kq * 8) ^ sxz]);
            #pragma unroll
            for (int ntl = 0; ntl < 2; ntl++)
                #pragma unroll
                for (int kt = 0; kt < 8; kt++)
                    acc[rt][ntl] = __builtin_amdgcn_mfma_f32_16x16x32_bf16(a[kt], B2[kt][ntl], acc[rt][ntl], 0, 0, 0);
        }
        // epilogue: bias+ELU -> atomic scatter-add
        #pragma unroll
        for (int ntl = 0; ntl < 2; ntl++) {
            int col = (w * 2 + ntl) * 16 + lm;
            float bias = b2v[col];
            #pragma unroll
            for (int rt = 0; rt < 4; rt++)
                #pragma unroll
                for (int r = 0; r < 4; r++) {
                    if (gi[rt][r] >= 0) {
                        float v = elu(acc[rt][ntl][r] + bias);
                        atomicAdd(out + (size_t)gi[rt][r] * 128 + col, v);
                    }
                }
        }
    }
}

extern "C" void kernel_launch(void* const* d_in, const int* in_sizes, int n_in,
                              void* d_out, int out_size, void* d_ws, size_t ws_size,
                              hipStream_t stream) {
    const float* x   = (const float*)d_in[0];
    const int*   sel = (const int*)d_in[1];
    const float* W0  = (const float*)d_in[2];
    const float* b0  = (const float*)d_in[3];
    const float* W1  = (const float*)d_in[4];
    const float* b1  = (const float*)d_in[5];
    const float* W2  = (const float*)d_in[6];
    const float* b2  = (const float*)d_in[7];
    float* out = (float*)d_out;
    short* wp  = (short*)d_ws;   // needs 262144 bytes

    pack_weights<<<512, 256, 0, stream>>>(W0, W1, W2, wp);
    copy_x<<<4096, 256, 0, stream>>>((const float4*)x, (float4*)out, NROWS * FDIM / 4);
    mlp_kernel<<<(MSEL + 63) / 64, 256, 0, stream>>>(x, sel, wp, b0, b1, b2, out);
}